// Round 13
// baseline (237.115 us; speedup 1.0000x reference)
//
#include <hip/hip_runtime.h>
#include <cstdint>

#define BB 16384
#define EPSR 1e-5f
#define TWO_PI 6.2831855f   // f32(2*pi) = 0x40C90FDB
#define L2E 1.44269504f     // log2(e)

// ---------------------------------------------------------------------------
// Threefry-2x32 (exact JAX implementation)
// ---------------------------------------------------------------------------
struct U2 { uint32_t x, y; };

__host__ __device__ constexpr uint32_t rotl32(uint32_t x, int r) {
  return (x << r) | (x >> (32 - r));
}

__host__ __device__ constexpr U2 tf2x32(uint32_t k0, uint32_t k1, uint32_t x0, uint32_t x1) {
  uint32_t ks0 = k0, ks1 = k1, ks2 = k0 ^ k1 ^ 0x1BD11BDAu;
  x0 += ks0; x1 += ks1;
  x0 += x1; x1 = rotl32(x1, 13); x1 ^= x0;
  x0 += x1; x1 = rotl32(x1, 15); x1 ^= x0;
  x0 += x1; x1 = rotl32(x1, 26); x1 ^= x0;
  x0 += x1; x1 = rotl32(x1, 6);  x1 ^= x0;
  x0 += ks1; x1 += ks2 + 1u;
  x0 += x1; x1 = rotl32(x1, 17); x1 ^= x0;
  x0 += x1; x1 = rotl32(x1, 29); x1 ^= x0;
  x0 += x1; x1 = rotl32(x1, 16); x1 ^= x0;
  x0 += x1; x1 = rotl32(x1, 24); x1 ^= x0;
  x0 += ks2; x1 += ks0 + 2u;
  x0 += x1; x1 = rotl32(x1, 13); x1 ^= x0;
  x0 += x1; x1 = rotl32(x1, 15); x1 ^= x0;
  x0 += x1; x1 = rotl32(x1, 26); x1 ^= x0;
  x0 += x1; x1 = rotl32(x1, 6);  x1 ^= x0;
  x0 += ks0; x1 += ks1 + 3u;
  x0 += x1; x1 = rotl32(x1, 17); x1 ^= x0;
  x0 += x1; x1 = rotl32(x1, 29); x1 ^= x0;
  x0 += x1; x1 = rotl32(x1, 16); x1 ^= x0;
  x0 += x1; x1 = rotl32(x1, 24); x1 ^= x0;
  x0 += ks1; x1 += ks2 + 4u;
  x0 += x1; x1 = rotl32(x1, 13); x1 ^= x0;
  x0 += x1; x1 = rotl32(x1, 15); x1 ^= x0;
  x0 += x1; x1 = rotl32(x1, 26); x1 ^= x0;
  x0 += x1; x1 = rotl32(x1, 6);  x1 ^= x0;
  x0 += ks2; x1 += ks0 + 5u;
  return U2{x0, x1};
}

static_assert(tf2x32(0u, 0u, 0u, 2u).x == 4146024105u, "threefry KAT A.x");
static_assert(tf2x32(0u, 0u, 0u, 2u).y == 2718843009u, "threefry KAT A.y");
static_assert(tf2x32(0u, 0u, 1u, 3u).x == 967050713u,  "threefry KAT B.x");
static_assert(tf2x32(0u, 0u, 1u, 3u).y == 1272950319u, "threefry KAT B.y");

// jax_threefry_partitionable=True: split(key,3)[i] = threefry(key, (0,i))
constexpr U2 KK1 = tf2x32(0u, 42u, 0u, 0u);
constexpr U2 KK2 = tf2x32(0u, 42u, 0u, 1u);
constexpr U2 KK3 = tf2x32(0u, 42u, 0u, 2u);

__device__ __forceinline__ uint32_t rbits(uint32_t ka, uint32_t kb, uint32_t n) {
  U2 r = tf2x32(ka, kb, 0u, n);
  return r.x ^ r.y;
}

__device__ __forceinline__ float u01f(uint32_t bits) {
  return __uint_as_float((bits >> 9) | 0x3F800000u) - 1.0f;
}

// RNG transforms: KEEP PRECISE (decision-critical, 14 lanes/block only)
__device__ __forceinline__ float gumbel_from(uint32_t bits) {
  #pragma clang fp contract(off)
  const float tiny = 1.17549435e-38f;
  float f = u01f(bits);
  float u = f * 1.0f + tiny;
  u = fmaxf(tiny, u);
  return -logf(-logf(u));
}

__device__ __forceinline__ float normal_from(uint32_t bits) {
  #pragma clang fp contract(off)
  const float lo = -0.99999994f;
  float f = u01f(bits);
  float u = f * 2.0f + lo;
  u = fmaxf(lo, u);
  float w = -log1pf(-(u * u));
  float p;
  if (w < 5.0f) {
    w = w - 2.5f;
    p = 2.81022636e-08f;
    p = 3.43273939e-07f  + p * w;
    p = -3.5233877e-06f  + p * w;
    p = -4.39150654e-06f + p * w;
    p = 0.00021858087f   + p * w;
    p = -0.00125372503f  + p * w;
    p = -0.00417768164f  + p * w;
    p = 0.246640727f     + p * w;
    p = 1.50140941f      + p * w;
  } else {
    w = sqrtf(w) - 3.0f;
    p = -0.000200214257f;
    p = 0.000100950558f  + p * w;
    p = 0.00134934322f   + p * w;
    p = -0.00367342844f  + p * w;
    p = 0.00573950773f   + p * w;
    p = -0.0076224613f   + p * w;
    p = 0.00943887047f   + p * w;
    p = 1.00167406f      + p * w;
    p = 2.83297682f      + p * w;
  }
  return 1.41421356f * (p * u);
}

// Fast-math helpers (validated r7-r12)
__device__ __forceinline__ float frcp(float x)  { return __builtin_amdgcn_rcpf(x); }
__device__ __forceinline__ float fexp(float x)  { return __expf(x); }
__device__ __forceinline__ float flog(float x)  { return __logf(x); }
__device__ __forceinline__ float fexp2(float x) {
#if __has_builtin(__builtin_amdgcn_exp2f)
  return __builtin_amdgcn_exp2f(x);
#else
  return __expf(x * 0.69314718f);
#endif
}
__device__ __forceinline__ float fsig(float x)  { return frcp(1.0f + fexp(-x)); }
__device__ __forceinline__ float flogsig(float x) {
  return fminf(x, 0.0f) - flog(1.0f + fexp(-fabsf(x)));
}

// ---------------------------------------------------------------------------
// DPP cross-lane reduction primitives (validated r8-r12).
// ---------------------------------------------------------------------------
template<int CTRL>
__device__ __forceinline__ float fdpp(float x) {
  return __int_as_float(__builtin_amdgcn_update_dpp(
      0, __float_as_int(x), CTRL, 0xF, 0xF, true));
}
template<int CTRL>
__device__ __forceinline__ int idpp(int x) {
  return __builtin_amdgcn_update_dpp(0, x, CTRL, 0xF, 0xF, true);
}
__device__ __forceinline__ float fswz16(float x) {
  return __int_as_float(__builtin_amdgcn_ds_swizzle(__float_as_int(x), 0x401F));
}
__device__ __forceinline__ int iswz16(int x) {
  return __builtin_amdgcn_ds_swizzle(x, 0x401F);
}

__device__ __forceinline__ float redh_sum(float x) {        // sum over h (quad)
  x += fdpp<0xB1>(x);
  x += fdpp<0x4E>(x);
  return x;
}
__device__ __forceinline__ float red8j_sum(float x) {       // sum over 8 j (quad-uniform in)
  x += fdpp<0x124>(x);
  x += fdpp<0x128>(x);
  x += fswz16(x);
  return x;
}
__device__ __forceinline__ float red64_sum(float x) {
  x += fdpp<0xB1>(x);
  x += fdpp<0x4E>(x);
  x += fdpp<0x124>(x);
  x += fdpp<0x128>(x);
  x += fswz16(x);
  x += __shfl_xor(x, 32);
  return x;
}

// ---------------------------------------------------------------------------
// Kernel A: featurize (validated r11/r12).
// ---------------------------------------------------------------------------
__global__ __launch_bounds__(256) void feat_kernel(
    const float* __restrict__ inp, const float* __restrict__ W1, const float* __restrict__ b1,
    const float* __restrict__ Wa, const float* __restrict__ ba,
    const float* __restrict__ Wv, const float* __restrict__ bv,
    float* __restrict__ feat) {
  __shared__ float xs[64][129];
  const int t = threadIdx.x;
  const int bl = t & 63;
  const int og = __builtin_amdgcn_readfirstlane(t >> 6);  // 0..3 wave-uniform
  const int btile = blockIdx.x >> 2;
  const int qtr = blockIdx.x & 3;
  const int b = btile * 64 + bl;
  const float4 in4 = *reinterpret_cast<const float4*>(inp + b * 4);
  #pragma unroll
  for (int jj = 0; jj < 32; ++jj) {
    int k = og * 32 + jj;
    float s = in4.x * W1[k * 4 + 0] + in4.y * W1[k * 4 + 1] +
              in4.z * W1[k * 4 + 2] + in4.w * W1[k * 4 + 3];
    s += b1[k];
    xs[bl][k] = fmaxf(s, 0.0f);
  }
  __syncthreads();
  #pragma unroll
  for (int pass = 0; pass < 2; ++pass) {
    const int o0 = qtr * 40 + og * 10 + pass * 5;   // wave-uniform
    const float* rr0; const float* rr1; const float* rr2;
    const float* rr3; const float* rr4;
    float bs[5];
    {
      int oo = o0 + 0; rr0 = (oo < 128) ? Wa + oo * 128 : Wv + (oo - 128) * 128;
      bs[0] = (oo < 128) ? ba[oo] : bv[oo - 128];
      oo = o0 + 1; rr1 = (oo < 128) ? Wa + oo * 128 : Wv + (oo - 128) * 128;
      bs[1] = (oo < 128) ? ba[oo] : bv[oo - 128];
      oo = o0 + 2; rr2 = (oo < 128) ? Wa + oo * 128 : Wv + (oo - 128) * 128;
      bs[2] = (oo < 128) ? ba[oo] : bv[oo - 128];
      oo = o0 + 3; rr3 = (oo < 128) ? Wa + oo * 128 : Wv + (oo - 128) * 128;
      bs[3] = (oo < 128) ? ba[oo] : bv[oo - 128];
      oo = o0 + 4; rr4 = (oo < 128) ? Wa + oo * 128 : Wv + (oo - 128) * 128;
      bs[4] = (oo < 128) ? ba[oo] : bv[oo - 128];
    }
    float s0 = 0.f, s1 = 0.f, s2 = 0.f, s3 = 0.f, s4 = 0.f;
    #pragma unroll 8
    for (int k = 0; k < 128; ++k) {
      float xv = xs[bl][k];
      s0 += rr0[k] * xv;
      s1 += rr1[k] * xv;
      s2 += rr2[k] * xv;
      s3 += rr3[k] * xv;
      s4 += rr4[k] * xv;
    }
    float* fo = feat + b * 160 + o0;
    fo[0] = s0 + bs[0]; fo[1] = s1 + bs[1]; fo[2] = s2 + bs[2];
    fo[3] = s3 + bs[3]; fo[4] = s4 + bs[4];
  }
}

// ---------------------------------------------------------------------------
// Kernel B: identical to r12 EXCEPT __launch_bounds__(128, 8) — occupancy
// experiment: VGPR is exactly 64, which supports 8 waves/SIMD.
// ---------------------------------------------------------------------------
__global__ __launch_bounds__(128, 8) void route_kernel(
    const float* __restrict__ feat,
    const float* __restrict__ R1W, const float* __restrict__ R1B,
    const float* __restrict__ R1bu, const float* __restrict__ R1bi,
    const float* __restrict__ R2W, const float* __restrict__ R2B,
    const float* __restrict__ R2bu, const float* __restrict__ R2bi,
    const float* __restrict__ inp, const float* __restrict__ sub_w,
    float* __restrict__ out) {
  const int lane = threadIdx.x & 63;
  const int w = threadIdx.x >> 6;   // wave 0 or 1
  const int b = blockIdx.x;
  const float* fb = feat + b * 160;

  __shared__ float4 r1a[3][2][32];    // [iter][wave][c] : {S, Sg, num, q2}
  __shared__ float  r1g[2][32];       // [wave][c] : iter0 sg partial
  __shared__ float  exS[2][2][8];     // [iter-1][wave][i] : sum_w
  __shared__ __align__(16) float s_mu1[32];
  __shared__ __align__(16) float s_f1[8];
  __shared__ float s_av[2];
  __shared__ int   s_ai[2];
  __shared__ float s_mu[2][4];

  // ======================= Routing 1: n_inp=32, n_out=8 ====================
  const int c = lane & 31;          // (j1,h1)
  const int ihalf = lane >> 5;
  const int q = w * 2 + ihalf;
  const int j1 = c >> 2, h1 = c & 3;
  const float w1r0 = R1W[(j1 * 4 + 0) * 4 + h1];
  const float w1r1 = R1W[(j1 * 4 + 1) * 4 + h1];
  const float w1r2 = R1W[(j1 * 4 + 2) * 4 + h1];
  const float w1r3 = R1W[(j1 * 4 + 3) * 4 + h1];
  const float bc1 = R1B[j1 * 4 + h1];
  const float bu1 = R1bu[j1], bi1 = R1bi[j1];

  // f0 dedupe: lane computes ONE sigmoid for i = w*16 + (lane&15)
  const float sfm = fsig(fb[128 + w * 16 + (lane & 15)]);

  float v1[8], f0[8];
  #pragma unroll
  for (int ii = 0; ii < 8; ++ii) {
    int i = q * 8 + ii;
    float4 m = *reinterpret_cast<const float4*>(fb + i * 4);
    v1[ii] = w1r0 * m.x + w1r1 * m.y + w1r2 * m.z + w1r3 * m.w + bc1;
    f0[ii] = __shfl(sfm, ihalf * 8 + ii);
  }

  float a1, mu1, sig1;
  {  // iteration 0: R = 1/8 (two-pass variance: no safe shift available)
    float S = 0.f, Sg = 0.f, num = 0.f;
    #pragma unroll
    for (int ii = 0; ii < 8; ++ii) {
      float D = f0[ii] * 0.125f;
      S += D;
      Sg += (f0[ii] - D);
      num += D * v1[ii];
    }
    S += __shfl_xor(S, 32); Sg += __shfl_xor(Sg, 32); num += __shfl_xor(num, 32);
    if (lane < 32) r1a[0][w][c] = make_float4(S, Sg, num, 0.f);
    __syncthreads();
    float4 o = r1a[0][w ^ 1][c];
    S += o.x; Sg += o.y; num += o.z;
    a1 = bu1 * S - bi1 * Sg;
    float inv = frcp(S + EPSR);
    mu1 = num * inv;
    float sg = 0.f;
    #pragma unroll
    for (int ii = 0; ii < 8; ++ii) {
      float D = f0[ii] * 0.125f;
      float tt = v1[ii] - mu1;
      sg += D * (tt * tt);
    }
    sg += __shfl_xor(sg, 32);
    if (lane < 32) r1g[w][c] = sg;
    __syncthreads();
    sg += r1g[w ^ 1][c];
    sig1 = sg * inv + EPSR;
  }
  #pragma unroll
  for (int it = 1; it < 3; ++it) {
    const bool needsig = (it == 1);   // last-iteration sigma is dead
    const float muold = mu1;
    float lsig = flogsig(a1);
    float lt1 = -(0.5f * flog(TWO_PI * sig1));
    float ltq = redh_sum(lt1);                  // quad-uniform sum of log-terms
    float C2 = (lsig + ltq) * L2E;              // per-j base-2 constant
    float nhis2 = (-0.5f * L2E) * frcp(sig1);
    float S = 0.f, Sg = 0.f, num = 0.f, q2 = 0.f;
    #pragma unroll
    for (int ii = 0; ii < 8; ++ii) {
      float tt = v1[ii] - muold;
      float d2 = tt * tt;
      float lp = d2 * nhis2;
      lp = redh_sum(lp);                  // sum over h (DPP quad)
      float e = fexp2(lp + C2);           // base-2, no max-sub
      float den = red8j_sum(e);
      float D = f0[ii] * (e * frcp(den));
      S += D;
      Sg += (f0[ii] - D);
      num += D * v1[ii];
      if (needsig) q2 += D * d2;          // shifted sum of squares (free d2)
    }
    S += __shfl_xor(S, 32); Sg += __shfl_xor(Sg, 32); num += __shfl_xor(num, 32);
    if (needsig) q2 += __shfl_xor(q2, 32);
    if (lane < 32) r1a[it][w][c] = make_float4(S, Sg, num, q2);
    __syncthreads();                      // ONE barrier per iteration
    float4 o = r1a[it][w ^ 1][c];
    S += o.x; Sg += o.y; num += o.z; q2 += o.w;
    a1 = bu1 * S - bi1 * Sg;
    float inv = frcp(S + EPSR);
    mu1 = num * inv;
    if (needsig) {
      // sigma^2*S = q2 - dm*(2t - dm*S), shift c = muold (dm small => stable)
      float dm = mu1 - muold;
      float tq = num - muold * S;
      float sraw = q2 - dm * (2.0f * tq - dm * S);
      sig1 = fmaxf(sraw, 0.0f) * inv + EPSR;
    }
  }

  // handoff: BOTH waves write identical mu1/f1 values (benign race);
  // own-wave ds ordering makes them visible without a barrier.
  if (lane < 32) {
    s_mu1[c] = mu1;
    if (h1 == 0) s_f1[j1] = fsig(a1);
  }
  float f1[8];
  {
    float4 fa = *reinterpret_cast<const float4*>(&s_f1[0]);
    float4 fbq = *reinterpret_cast<const float4*>(&s_f1[4]);
    f1[0] = fa.x; f1[1] = fa.y; f1[2] = fa.z; f1[3] = fa.w;
    f1[4] = fbq.x; f1[5] = fbq.y; f1[6] = fbq.z; f1[7] = fbq.w;
  }

  // ======================= Routing 2: n_inp=8, n_out=128 ===================
  const int j = w * 64 + lane;
  const float4 b4 = *reinterpret_cast<const float4*>(R2B + j * 4);
  const float bb2[4] = {b4.x, b4.y, b4.z, b4.w};
  const float bu2 = R2bu[j], bi2 = R2bi[j];

  float v2[8][4];
  #pragma unroll
  for (int i = 0; i < 8; ++i) {
    float4 mu4 = *reinterpret_cast<const float4*>(&s_mu1[i * 4]);
    const float4* wp = reinterpret_cast<const float4*>(R2W + i * 2048 + j * 16);
    float4 c0 = wp[0], c1 = wp[1], c2 = wp[2], c3 = wp[3];
    v2[i][0] = mu4.x * c0.x + mu4.y * c1.x + mu4.z * c2.x + mu4.w * c3.x + bb2[0];
    v2[i][1] = mu4.x * c0.y + mu4.y * c1.y + mu4.z * c2.y + mu4.w * c3.y + bb2[1];
    v2[i][2] = mu4.x * c0.z + mu4.y * c1.z + mu4.z * c2.z + mu4.w * c3.z + bb2[2];
    v2[i][3] = mu4.x * c0.w + mu4.y * c1.w + mu4.z * c2.w + mu4.w * c3.w + bb2[3];
  }

  float a2, mu[4], sg[4];
  {  // iteration 0: R = 1/128 (all lane-local)
    float S = 0.f, Sg = 0.f;
    #pragma unroll
    for (int i = 0; i < 8; ++i) {
      float D = f1[i] * 0.0078125f;
      S += D;
      Sg += (f1[i] - D);
    }
    a2 = bu2 * S - bi2 * Sg;
    float inv = frcp(S + EPSR);
    #pragma unroll
    for (int h = 0; h < 4; ++h) {
      float n = 0.f;
      #pragma unroll
      for (int i = 0; i < 8; ++i) n += (f1[i] * 0.0078125f) * v2[i][h];
      mu[h] = n * inv;
    }
    #pragma unroll
    for (int h = 0; h < 4; ++h) {
      float s2 = 0.f;
      #pragma unroll
      for (int i = 0; i < 8; ++i) {
        float D = f1[i] * 0.0078125f;
        float t = v2[i][h] - mu[h];
        s2 += D * (t * t);
      }
      sg[h] = s2 * inv + EPSR;
    }
  }

  float e[8], stw[8];
  #pragma unroll
  for (int it = 1; it < 3; ++it) {
    const bool needsig = (it == 1);
    float lsig = flogsig(a2);
    float is2[4], ltS = 0.f;
    #pragma unroll
    for (int h = 0; h < 4; ++h) {
      ltS += -(0.5f * flog(TWO_PI * sg[h]));
      is2[h] = (-0.5f * L2E) * frcp(sg[h]);
    }
    const float C2 = (lsig + ltS) * L2E;
    #pragma unroll
    for (int i = 0; i < 8; ++i) {
      float lp = C2;
      #pragma unroll
      for (int h = 0; h < 4; ++h) {
        float t = v2[i][h] - mu[h];
        lp = fmaf(t * t, is2[h], lp);
      }
      e[i] = fexp2(lp);                   // base-2, no max-sub
      stw[i] = red64_sum(e[i]);
    }
    if (lane == 0) {
      #pragma unroll
      for (int i = 0; i < 8; ++i) exS[it - 1][w][i] = stw[i];
    }
    __syncthreads();                      // one barrier per iteration
    float D[8];
    float SA = 0.f, SgS = 0.f;
    float n[4] = {0.f, 0.f, 0.f, 0.f};
    #pragma unroll
    for (int i = 0; i < 8; ++i) {
      float Stot = stw[i] + exS[it - 1][w ^ 1][i];
      float Dv = f1[i] * (e[i] * frcp(Stot));
      D[i] = Dv;
      SA += Dv;
      SgS += (f1[i] - Dv);
      #pragma unroll
      for (int h = 0; h < 4; ++h) n[h] += Dv * v2[i][h];
    }
    a2 = bu2 * SA - bi2 * SgS;
    float inv = frcp(SA + EPSR);
    #pragma unroll
    for (int h = 0; h < 4; ++h) mu[h] = n[h] * inv;
    if (needsig) {                        // lane-local two-pass variance
      #pragma unroll
      for (int h = 0; h < 4; ++h) {
        float s2 = 0.f;
        #pragma unroll
        for (int i = 0; i < 8; ++i) {
          float t = v2[i][h] - mu[h];
          s2 += D[i] * (t * t);
        }
        sg[h] = s2 * inv + EPSR;
      }
    }
  }

  // ===== value = max_j a2; idx = argmax (first occurrence); one barrier =====
  float bv = a2; int bj = j;
  {
    float ov; int oj;
    ov = fdpp<0xB1>(bv);  oj = idpp<0xB1>(bj);
    if (ov > bv || (ov == bv && oj < bj)) { bv = ov; bj = oj; }
    ov = fdpp<0x4E>(bv);  oj = idpp<0x4E>(bj);
    if (ov > bv || (ov == bv && oj < bj)) { bv = ov; bj = oj; }
    ov = fdpp<0x124>(bv); oj = idpp<0x124>(bj);
    if (ov > bv || (ov == bv && oj < bj)) { bv = ov; bj = oj; }
    ov = fdpp<0x128>(bv); oj = idpp<0x128>(bj);
    if (ov > bv || (ov == bv && oj < bj)) { bv = ov; bj = oj; }
    ov = fswz16(bv);      oj = iswz16(bj);
    if (ov > bv || (ov == bv && oj < bj)) { bv = ov; bj = oj; }
    ov = __shfl_xor(bv, 32); oj = __shfl_xor(bj, 32);
    if (ov > bv || (ov == bv && oj < bj)) { bv = ov; bj = oj; }
  }
  if (lane == 0) { s_av[w] = bv; s_ai[w] = bj; }
  if (j == bj) {  // per-wave winner publishes its mu
    s_mu[w][0] = mu[0]; s_mu[w][1] = mu[1]; s_mu[w][2] = mu[2]; s_mu[w][3] = mu[3];
  }
  __syncthreads();

  // =============================== finale (wave 0) =========================
  if (w == 0) {
    float av0 = s_av[0], av1 = s_av[1];
    float value; int winw;
    if (av1 > av0) { value = av1; winw = 1; }   // tie -> wave 0 (lower j)
    else           { value = av0; winw = 0; }
    float sel[4] = {s_mu[winw][0], s_mu[winw][1], s_mu[winw][2], s_mu[winw][3]};

    // parallel RNG draws: lanes 0..3 k1-gumbel, 4..11 k2-normal, 12..13 k3-gumbel
    float gu, no;
    {
      uint32_t ka, kb, nn;
      if (lane < 4)       { ka = KK1.x; kb = KK1.y; nn = (uint32_t)(b * 4 + lane); }
      else if (lane < 12) { ka = KK2.x; kb = KK2.y; nn = (uint32_t)(b * 8 + (lane - 4)); }
      else                { ka = KK3.x; kb = KK3.y; nn = (uint32_t)(b * 2 + (lane & 1)); }
      uint32_t bits = rbits(ka, kb, nn);
      gu = gumbel_from(bits);
      no = normal_from(bits);
    }
    const float g0 = __shfl(gu, 0), g1 = __shfl(gu, 1);
    const float g2 = __shfl(gu, 2), g3 = __shfl(gu, 3);
    float ep[8];
    #pragma unroll
    for (int i = 0; i < 8; ++i) ep[i] = __shfl(no, 4 + i);
    const float q0 = __shfl(gu, 12), q1 = __shfl(gu, 13);

    // softmax(sel) (keep max-sub: once per block, negligible)
    float mx = fmaxf(fmaxf(sel[0], sel[1]), fmaxf(sel[2], sel[3]));
    float ex[4], sesum = 0.f;
    #pragma unroll
    for (int cc = 0; cc < 4; ++cc) { ex[cc] = fexp(sel[cc] - mx); sesum += ex[cc]; }
    float rs0 = frcp(sesum);
    float lg1[4];
    #pragma unroll
    for (int cc = 0; cc < 4; ++cc) lg1[cc] = flog(ex[cc] * rs0 + 1e-20f);

    // sub_action = argmax(g + lg1), first occurrence
    float sc0 = g0 + lg1[0], sc1 = g1 + lg1[1];
    float sc2 = g2 + lg1[2], sc3 = g3 + lg1[3];
    int sub_action = 0;
    float bestsc = sc0;
    if (sc1 > bestsc) { bestsc = sc1; sub_action = 1; }
    if (sc2 > bestsc) { bestsc = sc2; sub_action = 2; }
    if (sc3 > bestsc) { bestsc = sc3; sub_action = 3; }

    // new_w, final = einsum
    float4 ib4 = *reinterpret_cast<const float4*>(inp + b * 4);
    float inb[4] = {ib4.x, ib4.y, ib4.z, ib4.w};
    float fin[2];
    #pragma unroll
    for (int o = 0; o < 2; ++o) {
      float acc = 0.f;
      #pragma unroll
      for (int i2 = 0; i2 < 4; ++i2) {
        float eps = ep[o * 4 + i2];
        float sw = sub_w[o * 4 + i2];
        float nw = (sub_action == 0) ? sw * eps : sw / eps;
        nw = fminf(fmaxf(nw, -1.0f), 1.0f);
        acc += inb[i2] * nw;
      }
      fin[o] = acc;
    }

    // softmax(final), categorical(k3)
    float mx2 = fmaxf(fin[0], fin[1]);
    float e0 = fexp(fin[0] - mx2), e1 = fexp(fin[1] - mx2);
    float rsum = frcp(e0 + e1);
    float lgp0 = flog(e0 * rsum + 1e-20f);
    float lgp1 = flog(e1 * rsum + 1e-20f);
    float s0 = q0 + lgp0;
    float s1 = q1 + lgp1;
    int action = (s1 > s0) ? 1 : 0;
    float log_prob = action ? lgp1 : lgp0;

    if (lane == 0) {
      out[b] = (float)action;
      out[BB + b] = log_prob;
      out[2 * BB + b] = value;
    }
  }
}

// ---------------------------------------------------------------------------
extern "C" void kernel_launch(void* const* d_in, const int* in_sizes, int n_in,
                              void* d_out, int out_size, void* d_ws, size_t ws_size,
                              hipStream_t stream) {
  const float* inp  = (const float*)d_in[0];
  const float* W1   = (const float*)d_in[1];
  const float* b1   = (const float*)d_in[2];
  const float* Wa   = (const float*)d_in[3];
  const float* ba   = (const float*)d_in[4];
  const float* Wv   = (const float*)d_in[5];
  const float* bv   = (const float*)d_in[6];
  const float* R1W  = (const float*)d_in[7];
  const float* R1B  = (const float*)d_in[8];
  const float* R1bu = (const float*)d_in[9];
  const float* R1bi = (const float*)d_in[10];
  const float* R2W  = (const float*)d_in[11];
  const float* R2B  = (const float*)d_in[12];
  const float* R2bu = (const float*)d_in[13];
  const float* R2bi = (const float*)d_in[14];
  const float* sub_w= (const float*)d_in[15];
  float* out = (float*)d_out;
  float* feat = (float*)d_ws;  // 16384*160*4 = 10.5 MB

  feat_kernel<<<(BB / 64) * 4, 256, 0, stream>>>(inp, W1, b1, Wa, ba, Wv, bv, feat);
  route_kernel<<<BB, 128, 0, stream>>>(feat, R1W, R1B, R1bu, R1bi,
                                       R2W, R2B, R2bu, R2bi, inp, sub_w, out);
}

// Round 14
// 140.078 us; speedup vs baseline: 1.6927x; 1.6927x over previous
//
#include <hip/hip_runtime.h>
#include <cstdint>

#define BB 16384
#define EPSR 1e-5f
#define TWO_PI 6.2831855f   // f32(2*pi) = 0x40C90FDB
#define L2E 1.44269504f     // log2(e)

// ---------------------------------------------------------------------------
// Threefry-2x32 (exact JAX implementation)
// ---------------------------------------------------------------------------
struct U2 { uint32_t x, y; };

__host__ __device__ constexpr uint32_t rotl32(uint32_t x, int r) {
  return (x << r) | (x >> (32 - r));
}

__host__ __device__ constexpr U2 tf2x32(uint32_t k0, uint32_t k1, uint32_t x0, uint32_t x1) {
  uint32_t ks0 = k0, ks1 = k1, ks2 = k0 ^ k1 ^ 0x1BD11BDAu;
  x0 += ks0; x1 += ks1;
  x0 += x1; x1 = rotl32(x1, 13); x1 ^= x0;
  x0 += x1; x1 = rotl32(x1, 15); x1 ^= x0;
  x0 += x1; x1 = rotl32(x1, 26); x1 ^= x0;
  x0 += x1; x1 = rotl32(x1, 6);  x1 ^= x0;
  x0 += ks1; x1 += ks2 + 1u;
  x0 += x1; x1 = rotl32(x1, 17); x1 ^= x0;
  x0 += x1; x1 = rotl32(x1, 29); x1 ^= x0;
  x0 += x1; x1 = rotl32(x1, 16); x1 ^= x0;
  x0 += x1; x1 = rotl32(x1, 24); x1 ^= x0;
  x0 += ks2; x1 += ks0 + 2u;
  x0 += x1; x1 = rotl32(x1, 13); x1 ^= x0;
  x0 += x1; x1 = rotl32(x1, 15); x1 ^= x0;
  x0 += x1; x1 = rotl32(x1, 26); x1 ^= x0;
  x0 += x1; x1 = rotl32(x1, 6);  x1 ^= x0;
  x0 += ks0; x1 += ks1 + 3u;
  x0 += x1; x1 = rotl32(x1, 17); x1 ^= x0;
  x0 += x1; x1 = rotl32(x1, 29); x1 ^= x0;
  x0 += x1; x1 = rotl32(x1, 16); x1 ^= x0;
  x0 += x1; x1 = rotl32(x1, 24); x1 ^= x0;
  x0 += ks1; x1 += ks2 + 4u;
  x0 += x1; x1 = rotl32(x1, 13); x1 ^= x0;
  x0 += x1; x1 = rotl32(x1, 15); x1 ^= x0;
  x0 += x1; x1 = rotl32(x1, 26); x1 ^= x0;
  x0 += x1; x1 = rotl32(x1, 6);  x1 ^= x0;
  x0 += ks2; x1 += ks0 + 5u;
  return U2{x0, x1};
}

static_assert(tf2x32(0u, 0u, 0u, 2u).x == 4146024105u, "threefry KAT A.x");
static_assert(tf2x32(0u, 0u, 0u, 2u).y == 2718843009u, "threefry KAT A.y");
static_assert(tf2x32(0u, 0u, 1u, 3u).x == 967050713u,  "threefry KAT B.x");
static_assert(tf2x32(0u, 0u, 1u, 3u).y == 1272950319u, "threefry KAT B.y");

// jax_threefry_partitionable=True: split(key,3)[i] = threefry(key, (0,i))
constexpr U2 KK1 = tf2x32(0u, 42u, 0u, 0u);
constexpr U2 KK2 = tf2x32(0u, 42u, 0u, 1u);
constexpr U2 KK3 = tf2x32(0u, 42u, 0u, 2u);

__device__ __forceinline__ uint32_t rbits(uint32_t ka, uint32_t kb, uint32_t n) {
  U2 r = tf2x32(ka, kb, 0u, n);
  return r.x ^ r.y;
}

__device__ __forceinline__ float u01f(uint32_t bits) {
  return __uint_as_float((bits >> 9) | 0x3F800000u) - 1.0f;
}

// RNG transforms: KEEP PRECISE (decision-critical, 14 lanes/block only)
__device__ __forceinline__ float gumbel_from(uint32_t bits) {
  #pragma clang fp contract(off)
  const float tiny = 1.17549435e-38f;
  float f = u01f(bits);
  float u = f * 1.0f + tiny;
  u = fmaxf(tiny, u);
  return -logf(-logf(u));
}

__device__ __forceinline__ float normal_from(uint32_t bits) {
  #pragma clang fp contract(off)
  const float lo = -0.99999994f;
  float f = u01f(bits);
  float u = f * 2.0f + lo;
  u = fmaxf(lo, u);
  float w = -log1pf(-(u * u));
  float p;
  if (w < 5.0f) {
    w = w - 2.5f;
    p = 2.81022636e-08f;
    p = 3.43273939e-07f  + p * w;
    p = -3.5233877e-06f  + p * w;
    p = -4.39150654e-06f + p * w;
    p = 0.00021858087f   + p * w;
    p = -0.00125372503f  + p * w;
    p = -0.00417768164f  + p * w;
    p = 0.246640727f     + p * w;
    p = 1.50140941f      + p * w;
  } else {
    w = sqrtf(w) - 3.0f;
    p = -0.000200214257f;
    p = 0.000100950558f  + p * w;
    p = 0.00134934322f   + p * w;
    p = -0.00367342844f  + p * w;
    p = 0.00573950773f   + p * w;
    p = -0.0076224613f   + p * w;
    p = 0.00943887047f   + p * w;
    p = 1.00167406f      + p * w;
    p = 2.83297682f      + p * w;
  }
  return 1.41421356f * (p * u);
}

// Fast-math helpers (validated r7-r12)
__device__ __forceinline__ float frcp(float x)  { return __builtin_amdgcn_rcpf(x); }
__device__ __forceinline__ float fexp(float x)  { return __expf(x); }
__device__ __forceinline__ float flog(float x)  { return __logf(x); }
__device__ __forceinline__ float fexp2(float x) {
#if __has_builtin(__builtin_amdgcn_exp2f)
  return __builtin_amdgcn_exp2f(x);
#else
  return __expf(x * 0.69314718f);
#endif
}
__device__ __forceinline__ float fsig(float x)  { return frcp(1.0f + fexp(-x)); }
__device__ __forceinline__ float flogsig(float x) {
  return fminf(x, 0.0f) - flog(1.0f + fexp(-fabsf(x)));
}

// ---------------------------------------------------------------------------
// DPP cross-lane reduction primitives (validated r8-r12).
// ---------------------------------------------------------------------------
template<int CTRL>
__device__ __forceinline__ float fdpp(float x) {
  return __int_as_float(__builtin_amdgcn_update_dpp(
      0, __float_as_int(x), CTRL, 0xF, 0xF, true));
}
template<int CTRL>
__device__ __forceinline__ int idpp(int x) {
  return __builtin_amdgcn_update_dpp(0, x, CTRL, 0xF, 0xF, true);
}
__device__ __forceinline__ float fswz16(float x) {
  return __int_as_float(__builtin_amdgcn_ds_swizzle(__float_as_int(x), 0x401F));
}
__device__ __forceinline__ int iswz16(int x) {
  return __builtin_amdgcn_ds_swizzle(x, 0x401F);
}

__device__ __forceinline__ float redh_sum(float x) {        // sum over h (quad)
  x += fdpp<0xB1>(x);
  x += fdpp<0x4E>(x);
  return x;
}
__device__ __forceinline__ float red8j_sum(float x) {       // sum over 8 j (quad-uniform in)
  x += fdpp<0x124>(x);
  x += fdpp<0x128>(x);
  x += fswz16(x);
  return x;
}
__device__ __forceinline__ float red64_sum(float x) {
  x += fdpp<0xB1>(x);
  x += fdpp<0x4E>(x);
  x += fdpp<0x124>(x);
  x += fdpp<0x128>(x);
  x += fswz16(x);
  x += __shfl_xor(x, 32);
  return x;
}

// ---------------------------------------------------------------------------
// Kernel A: featurize (validated r11/r12).
// ---------------------------------------------------------------------------
__global__ __launch_bounds__(256) void feat_kernel(
    const float* __restrict__ inp, const float* __restrict__ W1, const float* __restrict__ b1,
    const float* __restrict__ Wa, const float* __restrict__ ba,
    const float* __restrict__ Wv, const float* __restrict__ bv,
    float* __restrict__ feat) {
  __shared__ float xs[64][129];
  const int t = threadIdx.x;
  const int bl = t & 63;
  const int og = __builtin_amdgcn_readfirstlane(t >> 6);  // 0..3 wave-uniform
  const int btile = blockIdx.x >> 2;
  const int qtr = blockIdx.x & 3;
  const int b = btile * 64 + bl;
  const float4 in4 = *reinterpret_cast<const float4*>(inp + b * 4);
  #pragma unroll
  for (int jj = 0; jj < 32; ++jj) {
    int k = og * 32 + jj;
    float s = in4.x * W1[k * 4 + 0] + in4.y * W1[k * 4 + 1] +
              in4.z * W1[k * 4 + 2] + in4.w * W1[k * 4 + 3];
    s += b1[k];
    xs[bl][k] = fmaxf(s, 0.0f);
  }
  __syncthreads();
  #pragma unroll
  for (int pass = 0; pass < 2; ++pass) {
    const int o0 = qtr * 40 + og * 10 + pass * 5;   // wave-uniform
    const float* rr0; const float* rr1; const float* rr2;
    const float* rr3; const float* rr4;
    float bs[5];
    {
      int oo = o0 + 0; rr0 = (oo < 128) ? Wa + oo * 128 : Wv + (oo - 128) * 128;
      bs[0] = (oo < 128) ? ba[oo] : bv[oo - 128];
      oo = o0 + 1; rr1 = (oo < 128) ? Wa + oo * 128 : Wv + (oo - 128) * 128;
      bs[1] = (oo < 128) ? ba[oo] : bv[oo - 128];
      oo = o0 + 2; rr2 = (oo < 128) ? Wa + oo * 128 : Wv + (oo - 128) * 128;
      bs[2] = (oo < 128) ? ba[oo] : bv[oo - 128];
      oo = o0 + 3; rr3 = (oo < 128) ? Wa + oo * 128 : Wv + (oo - 128) * 128;
      bs[3] = (oo < 128) ? ba[oo] : bv[oo - 128];
      oo = o0 + 4; rr4 = (oo < 128) ? Wa + oo * 128 : Wv + (oo - 128) * 128;
      bs[4] = (oo < 128) ? ba[oo] : bv[oo - 128];
    }
    float s0 = 0.f, s1 = 0.f, s2 = 0.f, s3 = 0.f, s4 = 0.f;
    #pragma unroll 8
    for (int k = 0; k < 128; ++k) {
      float xv = xs[bl][k];
      s0 += rr0[k] * xv;
      s1 += rr1[k] * xv;
      s2 += rr2[k] * xv;
      s3 += rr3[k] * xv;
      s4 += rr4[k] * xv;
    }
    float* fo = feat + b * 160 + o0;
    fo[0] = s0 + bs[0]; fo[1] = s1 + bs[1]; fo[2] = s2 + bs[2];
    fo[3] = s3 + bs[3]; fo[4] = s4 + bs[4];
  }
}

// ---------------------------------------------------------------------------
// Kernel B: r12-validated configuration — __launch_bounds__(128, 4), VGPR 64,
// zero spill. (r13's (128,8) forced VGPR 32 -> 900 MB spill, 1.8x regression.)
// ---------------------------------------------------------------------------
__global__ __launch_bounds__(128, 4) void route_kernel(
    const float* __restrict__ feat,
    const float* __restrict__ R1W, const float* __restrict__ R1B,
    const float* __restrict__ R1bu, const float* __restrict__ R1bi,
    const float* __restrict__ R2W, const float* __restrict__ R2B,
    const float* __restrict__ R2bu, const float* __restrict__ R2bi,
    const float* __restrict__ inp, const float* __restrict__ sub_w,
    float* __restrict__ out) {
  const int lane = threadIdx.x & 63;
  const int w = threadIdx.x >> 6;   // wave 0 or 1
  const int b = blockIdx.x;
  const float* fb = feat + b * 160;

  __shared__ float4 r1a[3][2][32];    // [iter][wave][c] : {S, Sg, num, q2}
  __shared__ float  r1g[2][32];       // [wave][c] : iter0 sg partial
  __shared__ float  exS[2][2][8];     // [iter-1][wave][i] : sum_w
  __shared__ __align__(16) float s_mu1[32];
  __shared__ __align__(16) float s_f1[8];
  __shared__ float s_av[2];
  __shared__ int   s_ai[2];
  __shared__ float s_mu[2][4];

  // ======================= Routing 1: n_inp=32, n_out=8 ====================
  const int c = lane & 31;          // (j1,h1)
  const int ihalf = lane >> 5;
  const int q = w * 2 + ihalf;
  const int j1 = c >> 2, h1 = c & 3;
  const float w1r0 = R1W[(j1 * 4 + 0) * 4 + h1];
  const float w1r1 = R1W[(j1 * 4 + 1) * 4 + h1];
  const float w1r2 = R1W[(j1 * 4 + 2) * 4 + h1];
  const float w1r3 = R1W[(j1 * 4 + 3) * 4 + h1];
  const float bc1 = R1B[j1 * 4 + h1];
  const float bu1 = R1bu[j1], bi1 = R1bi[j1];

  // f0 dedupe: lane computes ONE sigmoid for i = w*16 + (lane&15)
  const float sfm = fsig(fb[128 + w * 16 + (lane & 15)]);

  float v1[8], f0[8];
  #pragma unroll
  for (int ii = 0; ii < 8; ++ii) {
    int i = q * 8 + ii;
    float4 m = *reinterpret_cast<const float4*>(fb + i * 4);
    v1[ii] = w1r0 * m.x + w1r1 * m.y + w1r2 * m.z + w1r3 * m.w + bc1;
    f0[ii] = __shfl(sfm, ihalf * 8 + ii);
  }

  float a1, mu1, sig1;
  {  // iteration 0: R = 1/8 (two-pass variance: no safe shift available)
    float S = 0.f, Sg = 0.f, num = 0.f;
    #pragma unroll
    for (int ii = 0; ii < 8; ++ii) {
      float D = f0[ii] * 0.125f;
      S += D;
      Sg += (f0[ii] - D);
      num += D * v1[ii];
    }
    S += __shfl_xor(S, 32); Sg += __shfl_xor(Sg, 32); num += __shfl_xor(num, 32);
    if (lane < 32) r1a[0][w][c] = make_float4(S, Sg, num, 0.f);
    __syncthreads();
    float4 o = r1a[0][w ^ 1][c];
    S += o.x; Sg += o.y; num += o.z;
    a1 = bu1 * S - bi1 * Sg;
    float inv = frcp(S + EPSR);
    mu1 = num * inv;
    float sg = 0.f;
    #pragma unroll
    for (int ii = 0; ii < 8; ++ii) {
      float D = f0[ii] * 0.125f;
      float tt = v1[ii] - mu1;
      sg += D * (tt * tt);
    }
    sg += __shfl_xor(sg, 32);
    if (lane < 32) r1g[w][c] = sg;
    __syncthreads();
    sg += r1g[w ^ 1][c];
    sig1 = sg * inv + EPSR;
  }
  #pragma unroll
  for (int it = 1; it < 3; ++it) {
    const bool needsig = (it == 1);   // last-iteration sigma is dead
    const float muold = mu1;
    float lsig = flogsig(a1);
    float lt1 = -(0.5f * flog(TWO_PI * sig1));
    float ltq = redh_sum(lt1);                  // quad-uniform sum of log-terms
    float C2 = (lsig + ltq) * L2E;              // per-j base-2 constant
    float nhis2 = (-0.5f * L2E) * frcp(sig1);
    float S = 0.f, Sg = 0.f, num = 0.f, q2 = 0.f;
    #pragma unroll
    for (int ii = 0; ii < 8; ++ii) {
      float tt = v1[ii] - muold;
      float d2 = tt * tt;
      float lp = d2 * nhis2;
      lp = redh_sum(lp);                  // sum over h (DPP quad)
      float e = fexp2(lp + C2);           // base-2, no max-sub
      float den = red8j_sum(e);
      float D = f0[ii] * (e * frcp(den));
      S += D;
      Sg += (f0[ii] - D);
      num += D * v1[ii];
      if (needsig) q2 += D * d2;          // shifted sum of squares (free d2)
    }
    S += __shfl_xor(S, 32); Sg += __shfl_xor(Sg, 32); num += __shfl_xor(num, 32);
    if (needsig) q2 += __shfl_xor(q2, 32);
    if (lane < 32) r1a[it][w][c] = make_float4(S, Sg, num, q2);
    __syncthreads();                      // ONE barrier per iteration
    float4 o = r1a[it][w ^ 1][c];
    S += o.x; Sg += o.y; num += o.z; q2 += o.w;
    a1 = bu1 * S - bi1 * Sg;
    float inv = frcp(S + EPSR);
    mu1 = num * inv;
    if (needsig) {
      // sigma^2*S = q2 - dm*(2t - dm*S), shift c = muold (dm small => stable)
      float dm = mu1 - muold;
      float tq = num - muold * S;
      float sraw = q2 - dm * (2.0f * tq - dm * S);
      sig1 = fmaxf(sraw, 0.0f) * inv + EPSR;
    }
  }

  // handoff: BOTH waves write identical mu1/f1 values (benign race);
  // own-wave ds ordering makes them visible without a barrier.
  if (lane < 32) {
    s_mu1[c] = mu1;
    if (h1 == 0) s_f1[j1] = fsig(a1);
  }
  float f1[8];
  {
    float4 fa = *reinterpret_cast<const float4*>(&s_f1[0]);
    float4 fbq = *reinterpret_cast<const float4*>(&s_f1[4]);
    f1[0] = fa.x; f1[1] = fa.y; f1[2] = fa.z; f1[3] = fa.w;
    f1[4] = fbq.x; f1[5] = fbq.y; f1[6] = fbq.z; f1[7] = fbq.w;
  }

  // ======================= Routing 2: n_inp=8, n_out=128 ===================
  const int j = w * 64 + lane;
  const float4 b4 = *reinterpret_cast<const float4*>(R2B + j * 4);
  const float bb2[4] = {b4.x, b4.y, b4.z, b4.w};
  const float bu2 = R2bu[j], bi2 = R2bi[j];

  float v2[8][4];
  #pragma unroll
  for (int i = 0; i < 8; ++i) {
    float4 mu4 = *reinterpret_cast<const float4*>(&s_mu1[i * 4]);
    const float4* wp = reinterpret_cast<const float4*>(R2W + i * 2048 + j * 16);
    float4 c0 = wp[0], c1 = wp[1], c2 = wp[2], c3 = wp[3];
    v2[i][0] = mu4.x * c0.x + mu4.y * c1.x + mu4.z * c2.x + mu4.w * c3.x + bb2[0];
    v2[i][1] = mu4.x * c0.y + mu4.y * c1.y + mu4.z * c2.y + mu4.w * c3.y + bb2[1];
    v2[i][2] = mu4.x * c0.z + mu4.y * c1.z + mu4.z * c2.z + mu4.w * c3.z + bb2[2];
    v2[i][3] = mu4.x * c0.w + mu4.y * c1.w + mu4.z * c2.w + mu4.w * c3.w + bb2[3];
  }

  float a2, mu[4], sg[4];
  {  // iteration 0: R = 1/128 (all lane-local)
    float S = 0.f, Sg = 0.f;
    #pragma unroll
    for (int i = 0; i < 8; ++i) {
      float D = f1[i] * 0.0078125f;
      S += D;
      Sg += (f1[i] - D);
    }
    a2 = bu2 * S - bi2 * Sg;
    float inv = frcp(S + EPSR);
    #pragma unroll
    for (int h = 0; h < 4; ++h) {
      float n = 0.f;
      #pragma unroll
      for (int i = 0; i < 8; ++i) n += (f1[i] * 0.0078125f) * v2[i][h];
      mu[h] = n * inv;
    }
    #pragma unroll
    for (int h = 0; h < 4; ++h) {
      float s2 = 0.f;
      #pragma unroll
      for (int i = 0; i < 8; ++i) {
        float D = f1[i] * 0.0078125f;
        float t = v2[i][h] - mu[h];
        s2 += D * (t * t);
      }
      sg[h] = s2 * inv + EPSR;
    }
  }

  float e[8], stw[8];
  #pragma unroll
  for (int it = 1; it < 3; ++it) {
    const bool needsig = (it == 1);
    float lsig = flogsig(a2);
    float is2[4], ltS = 0.f;
    #pragma unroll
    for (int h = 0; h < 4; ++h) {
      ltS += -(0.5f * flog(TWO_PI * sg[h]));
      is2[h] = (-0.5f * L2E) * frcp(sg[h]);
    }
    const float C2 = (lsig + ltS) * L2E;
    #pragma unroll
    for (int i = 0; i < 8; ++i) {
      float lp = C2;
      #pragma unroll
      for (int h = 0; h < 4; ++h) {
        float t = v2[i][h] - mu[h];
        lp = fmaf(t * t, is2[h], lp);
      }
      e[i] = fexp2(lp);                   // base-2, no max-sub
      stw[i] = red64_sum(e[i]);
    }
    if (lane == 0) {
      #pragma unroll
      for (int i = 0; i < 8; ++i) exS[it - 1][w][i] = stw[i];
    }
    __syncthreads();                      // one barrier per iteration
    float D[8];
    float SA = 0.f, SgS = 0.f;
    float n[4] = {0.f, 0.f, 0.f, 0.f};
    #pragma unroll
    for (int i = 0; i < 8; ++i) {
      float Stot = stw[i] + exS[it - 1][w ^ 1][i];
      float Dv = f1[i] * (e[i] * frcp(Stot));
      D[i] = Dv;
      SA += Dv;
      SgS += (f1[i] - Dv);
      #pragma unroll
      for (int h = 0; h < 4; ++h) n[h] += Dv * v2[i][h];
    }
    a2 = bu2 * SA - bi2 * SgS;
    float inv = frcp(SA + EPSR);
    #pragma unroll
    for (int h = 0; h < 4; ++h) mu[h] = n[h] * inv;
    if (needsig) {                        // lane-local two-pass variance
      #pragma unroll
      for (int h = 0; h < 4; ++h) {
        float s2 = 0.f;
        #pragma unroll
        for (int i = 0; i < 8; ++i) {
          float t = v2[i][h] - mu[h];
          s2 += D[i] * (t * t);
        }
        sg[h] = s2 * inv + EPSR;
      }
    }
  }

  // ===== value = max_j a2; idx = argmax (first occurrence); one barrier =====
  float bv = a2; int bj = j;
  {
    float ov; int oj;
    ov = fdpp<0xB1>(bv);  oj = idpp<0xB1>(bj);
    if (ov > bv || (ov == bv && oj < bj)) { bv = ov; bj = oj; }
    ov = fdpp<0x4E>(bv);  oj = idpp<0x4E>(bj);
    if (ov > bv || (ov == bv && oj < bj)) { bv = ov; bj = oj; }
    ov = fdpp<0x124>(bv); oj = idpp<0x124>(bj);
    if (ov > bv || (ov == bv && oj < bj)) { bv = ov; bj = oj; }
    ov = fdpp<0x128>(bv); oj = idpp<0x128>(bj);
    if (ov > bv || (ov == bv && oj < bj)) { bv = ov; bj = oj; }
    ov = fswz16(bv);      oj = iswz16(bj);
    if (ov > bv || (ov == bv && oj < bj)) { bv = ov; bj = oj; }
    ov = __shfl_xor(bv, 32); oj = __shfl_xor(bj, 32);
    if (ov > bv || (ov == bv && oj < bj)) { bv = ov; bj = oj; }
  }
  if (lane == 0) { s_av[w] = bv; s_ai[w] = bj; }
  if (j == bj) {  // per-wave winner publishes its mu
    s_mu[w][0] = mu[0]; s_mu[w][1] = mu[1]; s_mu[w][2] = mu[2]; s_mu[w][3] = mu[3];
  }
  __syncthreads();

  // =============================== finale (wave 0) =========================
  if (w == 0) {
    float av0 = s_av[0], av1 = s_av[1];
    float value; int winw;
    if (av1 > av0) { value = av1; winw = 1; }   // tie -> wave 0 (lower j)
    else           { value = av0; winw = 0; }
    float sel[4] = {s_mu[winw][0], s_mu[winw][1], s_mu[winw][2], s_mu[winw][3]};

    // parallel RNG draws: lanes 0..3 k1-gumbel, 4..11 k2-normal, 12..13 k3-gumbel
    float gu, no;
    {
      uint32_t ka, kb, nn;
      if (lane < 4)       { ka = KK1.x; kb = KK1.y; nn = (uint32_t)(b * 4 + lane); }
      else if (lane < 12) { ka = KK2.x; kb = KK2.y; nn = (uint32_t)(b * 8 + (lane - 4)); }
      else                { ka = KK3.x; kb = KK3.y; nn = (uint32_t)(b * 2 + (lane & 1)); }
      uint32_t bits = rbits(ka, kb, nn);
      gu = gumbel_from(bits);
      no = normal_from(bits);
    }
    const float g0 = __shfl(gu, 0), g1 = __shfl(gu, 1);
    const float g2 = __shfl(gu, 2), g3 = __shfl(gu, 3);
    float ep[8];
    #pragma unroll
    for (int i = 0; i < 8; ++i) ep[i] = __shfl(no, 4 + i);
    const float q0 = __shfl(gu, 12), q1 = __shfl(gu, 13);

    // softmax(sel) (keep max-sub: once per block, negligible)
    float mx = fmaxf(fmaxf(sel[0], sel[1]), fmaxf(sel[2], sel[3]));
    float ex[4], sesum = 0.f;
    #pragma unroll
    for (int cc = 0; cc < 4; ++cc) { ex[cc] = fexp(sel[cc] - mx); sesum += ex[cc]; }
    float rs0 = frcp(sesum);
    float lg1[4];
    #pragma unroll
    for (int cc = 0; cc < 4; ++cc) lg1[cc] = flog(ex[cc] * rs0 + 1e-20f);

    // sub_action = argmax(g + lg1), first occurrence
    float sc0 = g0 + lg1[0], sc1 = g1 + lg1[1];
    float sc2 = g2 + lg1[2], sc3 = g3 + lg1[3];
    int sub_action = 0;
    float bestsc = sc0;
    if (sc1 > bestsc) { bestsc = sc1; sub_action = 1; }
    if (sc2 > bestsc) { bestsc = sc2; sub_action = 2; }
    if (sc3 > bestsc) { bestsc = sc3; sub_action = 3; }

    // new_w, final = einsum
    float4 ib4 = *reinterpret_cast<const float4*>(inp + b * 4);
    float inb[4] = {ib4.x, ib4.y, ib4.z, ib4.w};
    float fin[2];
    #pragma unroll
    for (int o = 0; o < 2; ++o) {
      float acc = 0.f;
      #pragma unroll
      for (int i2 = 0; i2 < 4; ++i2) {
        float eps = ep[o * 4 + i2];
        float sw = sub_w[o * 4 + i2];
        float nw = (sub_action == 0) ? sw * eps : sw / eps;
        nw = fminf(fmaxf(nw, -1.0f), 1.0f);
        acc += inb[i2] * nw;
      }
      fin[o] = acc;
    }

    // softmax(final), categorical(k3)
    float mx2 = fmaxf(fin[0], fin[1]);
    float e0 = fexp(fin[0] - mx2), e1 = fexp(fin[1] - mx2);
    float rsum = frcp(e0 + e1);
    float lgp0 = flog(e0 * rsum + 1e-20f);
    float lgp1 = flog(e1 * rsum + 1e-20f);
    float s0 = q0 + lgp0;
    float s1 = q1 + lgp1;
    int action = (s1 > s0) ? 1 : 0;
    float log_prob = action ? lgp1 : lgp0;

    if (lane == 0) {
      out[b] = (float)action;
      out[BB + b] = log_prob;
      out[2 * BB + b] = value;
    }
  }
}

// ---------------------------------------------------------------------------
extern "C" void kernel_launch(void* const* d_in, const int* in_sizes, int n_in,
                              void* d_out, int out_size, void* d_ws, size_t ws_size,
                              hipStream_t stream) {
  const float* inp  = (const float*)d_in[0];
  const float* W1   = (const float*)d_in[1];
  const float* b1   = (const float*)d_in[2];
  const float* Wa   = (const float*)d_in[3];
  const float* ba   = (const float*)d_in[4];
  const float* Wv   = (const float*)d_in[5];
  const float* bv   = (const float*)d_in[6];
  const float* R1W  = (const float*)d_in[7];
  const float* R1B  = (const float*)d_in[8];
  const float* R1bu = (const float*)d_in[9];
  const float* R1bi = (const float*)d_in[10];
  const float* R2W  = (const float*)d_in[11];
  const float* R2B  = (const float*)d_in[12];
  const float* R2bu = (const float*)d_in[13];
  const float* R2bi = (const float*)d_in[14];
  const float* sub_w= (const float*)d_in[15];
  float* out = (float*)d_out;
  float* feat = (float*)d_ws;  // 16384*160*4 = 10.5 MB

  feat_kernel<<<(BB / 64) * 4, 256, 0, stream>>>(inp, W1, b1, Wa, ba, Wv, bv, feat);
  route_kernel<<<BB, 128, 0, stream>>>(feat, R1W, R1B, R1bu, R1bi,
                                       R2W, R2B, R2bu, R2bi, inp, sub_w, out);
}